// Round 12
// baseline (209.520 us; speedup 1.0000x reference)
//
#include <hip/hip_runtime.h>

// L2O optimizer fused kernel — R12: R11 with the NT-store type fix
// (__builtin_nontemporal_store needs a clang ext_vector pointer, not HIP's
// float4 class). Levers under test, unchanged from R11:
//  (a) nontemporal stores on all outputs: 410MB of never-read writes bypass
//      L2/L3 allocation -> input lines stay resident (read L3-hit was ~50%).
//  (b) bijective XCD-aware block swizzle (T1, m204): contiguous element range
//      per XCD -> per-XCD L2/DRAM-page locality.
// C/D layout (HW-verified): col = lane&15, row = (lane>>4)*4 + reg.

typedef __attribute__((ext_vector_type(8))) short bf16x8;
typedef __attribute__((ext_vector_type(4))) short bf16x4;
typedef __attribute__((ext_vector_type(4))) float f32x4;

#define HH 32
#define LL 10
#define NG 128
#define NW 8            // waves per block
#define BLK 512         // threads per block
#define TPS 36          // tbuf row stride in shorts (72B; keeps 16B alignment)

__device__ __forceinline__ short f2bf(float x) {
  __bf16 b = (__bf16)x;
  return __builtin_bit_cast(short, b);
}
__device__ __forceinline__ float fsig(float x) {
  return __builtin_amdgcn_rcpf(1.0f + __expf(-x));
}
__device__ __forceinline__ float ftanh(float x) {
  return fmaf(2.0f, __builtin_amdgcn_rcpf(1.0f + __expf(-2.0f * x)), -1.0f);
}
#define LDS_FENCE() asm volatile("s_waitcnt lgkmcnt(0)" ::: "memory")
// NT stores: clang ext_vector pointee required (float4 = HIP class is invalid)
#define NTST4(p, v) __builtin_nontemporal_store((v), reinterpret_cast<f32x4*>(p))
#define NTST1(p, v) __builtin_nontemporal_store((v), (p))

// 2-deep prefetch of the h-streams (consumed first, by the MFMAs)
#define LOADH(P, STV) do {                                                    \
    const size_t ro_ = (size_t)(ebase + (STV) * 16 + col) * HH + 8 * g;       \
    P##hv0 = reinterpret_cast<const float4*>(h0 + ro_)[0];                    \
    P##hv1 = reinterpret_cast<const float4*>(h0 + ro_)[1];                    \
    P##wv0 = reinterpret_cast<const float4*>(h1 + ro_)[0];                    \
    P##wv1 = reinterpret_cast<const float4*>(h1 + ro_)[1];                    \
  } while (0)

#define COMPUTE(P, STV) do {                                                  \
    const int m16_ = ebase + (STV) * 16;                                      \
    const size_t ro_ = (size_t)(m16_ + col) * HH;                             \
    /* c-streams: aligned row-segment loads (k=4g..4g+3 and 16+4g..16+4g+3) */\
    float4 cv0 = *reinterpret_cast<const float4*>(c0 + ro_ + 4 * g);          \
    float4 cv1 = *reinterpret_cast<const float4*>(c0 + ro_ + 16 + 4 * g);     \
    float4 dv0 = *reinterpret_cast<const float4*>(c1 + ro_ + 4 * g);          \
    float4 dv1 = *reinterpret_cast<const float4*>(c1 + ro_ + 16 + 4 * g);     \
    /* B operands (states) */                                                 \
    bf16x8 b_t = {0, 0, 0, 0, 0, 0, 0, 0};                                    \
    if (g < 2) b_t = *reinterpret_cast<const bf16x8*>(&tsg[w][(STV) * 16 + col][8 * g]); \
    bf16x8 b_h0;                                                              \
    b_h0[0] = f2bf(P##hv0.x); b_h0[1] = f2bf(P##hv0.y);                       \
    b_h0[2] = f2bf(P##hv0.z); b_h0[3] = f2bf(P##hv0.w);                       \
    b_h0[4] = f2bf(P##hv1.x); b_h0[5] = f2bf(P##hv1.y);                       \
    b_h0[6] = f2bf(P##hv1.z); b_h0[7] = f2bf(P##hv1.w);                       \
    f32x4 acc[8];                                                             \
    _Pragma("unroll")                                                         \
    for (int nt = 0; nt < 8; ++nt) { f32x4 z = {0.f, 0.f, 0.f, 0.f}; acc[nt] = z; } \
    _Pragma("unroll")                                                         \
    for (int nt = 0; nt < 8; ++nt) {                                          \
      bf16x8 a_ih = *reinterpret_cast<const bf16x8*>(&wih0L[g & 1][nt * 16 + col][0]); \
      acc[nt] = __builtin_amdgcn_mfma_f32_16x16x32_bf16(a_ih, b_t, acc[nt], 0, 0, 0);  \
      bf16x8 a_hh = *reinterpret_cast<const bf16x8*>(&whh0L[g][nt * 16 + col][0]);     \
      acc[nt] = __builtin_amdgcn_mfma_f32_16x16x32_bf16(a_hh, b_h0, acc[nt], 0, 0, 0); \
    }                                                                         \
    /* layer-0 gates: lane-local, element e=col, k=16kk+4g+r */               \
    float hnv[2][4], cnv[2][4];                                               \
    _Pragma("unroll")                                                         \
    for (int kk = 0; kk < 2; ++kk)                                            \
      _Pragma("unroll")                                                       \
      for (int r = 0; r < 4; ++r) {                                           \
        float iv = fsig(acc[kk][r]);                                          \
        float fv = fsig(acc[2 + kk][r]);                                      \
        float gv = ftanh(acc[4 + kk][r]);                                     \
        float ov = fsig(acc[6 + kk][r]);                                      \
        float cp = kk ? cv1[r] : cv0[r];                                      \
        float cn = fv * cp + iv * gv;                                         \
        cnv[kk][r] = cn;                                                      \
        hnv[kk][r] = ov * ftanh(cn);                                          \
      }                                                                       \
    { /* direct aligned NT stores, no transpose */                            \
      f32x4 s0 = {cnv[0][0], cnv[0][1], cnv[0][2], cnv[0][3]};                \
      f32x4 s1 = {cnv[1][0], cnv[1][1], cnv[1][2], cnv[1][3]};                \
      NTST4(c0out + ro_ + 4 * g, s0);                                         \
      NTST4(c0out + ro_ + 16 + 4 * g, s1);                                    \
      f32x4 t0 = {hnv[0][0], hnv[0][1], hnv[0][2], hnv[0][3]};                \
      f32x4 t1 = {hnv[1][0], hnv[1][1], hnv[1][2], hnv[1][3]};                \
      NTST4(h0out + ro_ + 4 * g, t0);                                         \
      NTST4(h0out + ro_ + 16 + 4 * g, t1);                                    \
    }                                                                         \
    /* h0n k-regroup via bf16 tbuf: write own k-positions, read k=8g..8g+7 */ \
    {                                                                         \
      bf16x4 p0 = {f2bf(hnv[0][0]), f2bf(hnv[0][1]), f2bf(hnv[0][2]), f2bf(hnv[0][3])}; \
      bf16x4 p1 = {f2bf(hnv[1][0]), f2bf(hnv[1][1]), f2bf(hnv[1][2]), f2bf(hnv[1][3])}; \
      *reinterpret_cast<bf16x4*>(&tbuf[w][col][4 * g])      = p0;             \
      *reinterpret_cast<bf16x4*>(&tbuf[w][col][16 + 4 * g]) = p1;             \
    }                                                                         \
    LDS_FENCE();                                                              \
    bf16x8 b_hn = *reinterpret_cast<const bf16x8*>(&tbuf[w][col][8 * g]);     \
    LDS_FENCE();   /* WAR: reads complete before next tile's writes */        \
    bf16x8 b_h1;                                                              \
    b_h1[0] = f2bf(P##wv0.x); b_h1[1] = f2bf(P##wv0.y);                       \
    b_h1[2] = f2bf(P##wv0.z); b_h1[3] = f2bf(P##wv0.w);                       \
    b_h1[4] = f2bf(P##wv1.x); b_h1[5] = f2bf(P##wv1.y);                       \
    b_h1[6] = f2bf(P##wv1.z); b_h1[7] = f2bf(P##wv1.w);                       \
    _Pragma("unroll")                                                         \
    for (int nt = 0; nt < 8; ++nt) acc[nt] = biasv1[nt];                      \
    _Pragma("unroll")                                                         \
    for (int nt = 0; nt < 8; ++nt) {                                          \
      bf16x8 a_ih = *reinterpret_cast<const bf16x8*>(&wih1L[g][nt * 16 + col][0]);     \
      acc[nt] = __builtin_amdgcn_mfma_f32_16x16x32_bf16(a_ih, b_hn, acc[nt], 0, 0, 0); \
      bf16x8 a_hh = *reinterpret_cast<const bf16x8*>(&whh1L[g][nt * 16 + col][0]);     \
      acc[nt] = __builtin_amdgcn_mfma_f32_16x16x32_bf16(a_hh, b_h1, acc[nt], 0, 0, 0); \
    }                                                                         \
    _Pragma("unroll")                                                         \
    for (int kk = 0; kk < 2; ++kk)                                            \
      _Pragma("unroll")                                                       \
      for (int r = 0; r < 4; ++r) {                                           \
        float iv = fsig(acc[kk][r]);                                          \
        float fv = fsig(acc[2 + kk][r]);                                      \
        float gv = ftanh(acc[4 + kk][r]);                                     \
        float ov = fsig(acc[6 + kk][r]);                                      \
        float cp = kk ? dv1[r] : dv0[r];                                      \
        float cn = fv * cp + iv * gv;                                         \
        cnv[kk][r] = cn;                                                      \
        hnv[kk][r] = ov * ftanh(cn);                                          \
      }                                                                       \
    {                                                                         \
      f32x4 s0 = {cnv[0][0], cnv[0][1], cnv[0][2], cnv[0][3]};                \
      f32x4 s1 = {cnv[1][0], cnv[1][1], cnv[1][2], cnv[1][3]};                \
      NTST4(c1out + ro_ + 4 * g, s0);                                         \
      NTST4(c1out + ro_ + 16 + 4 * g, s1);                                    \
      f32x4 t0 = {hnv[0][0], hnv[0][1], hnv[0][2], hnv[0][3]};                \
      f32x4 t1 = {hnv[1][0], hnv[1][1], hnv[1][2], hnv[1][3]};                \
      NTST4(h1out + ro_ + 4 * g, t0);                                         \
      NTST4(h1out + ro_ + 16 + 4 * g, t1);                                    \
    }                                                                         \
    float dsum = 0.f;                                                         \
    _Pragma("unroll")                                                         \
    for (int r = 0; r < 4; ++r)                                               \
      dsum += hnv[0][r] * wfcA[r] + hnv[1][r] * wfcB[r];                      \
    dsum += __shfl_xor(dsum, 16, 64);                                         \
    dsum += __shfl_xor(dsum, 32, 64);                                         \
    if (g == 0) {                                                             \
      float xv = x[m16_ + col];                                               \
      float dv = dsum + bfcv;                                                 \
      NTST1(dout + m16_ + col, dv);                                           \
      NTST1(xout + m16_ + col, xv + dv);                                      \
    }                                                                         \
  } while (0)

__global__ __launch_bounds__(BLK, 2) void l2o_fused(
    const float* __restrict__ x, const float* __restrict__ grad,
    const float* __restrict__ h0, const float* __restrict__ c0,
    const float* __restrict__ h1, const float* __restrict__ c1,
    const float* __restrict__ W1, const float* __restrict__ b1,
    const float* __restrict__ W2, const float* __restrict__ b2,
    const float* __restrict__ Wih0, const float* __restrict__ Whh0,
    const float* __restrict__ bih0, const float* __restrict__ bhh0,
    const float* __restrict__ Wih1, const float* __restrict__ Whh1,
    const float* __restrict__ bih1, const float* __restrict__ bhh1,
    const float* __restrict__ Wfc, const float* __restrict__ bfc,
    float* __restrict__ out, int BNi)
{
  const size_t BN = (size_t)BNi;
  float* __restrict__ xout  = out;
  float* __restrict__ h0out = out + BN;
  float* __restrict__ c0out = out + BN + BN * HH;
  float* __restrict__ h1out = out + BN + 2 * BN * HH;
  float* __restrict__ c1out = out + BN + 3 * BN * HH;
  float* __restrict__ dout  = out + BN + 4 * BN * HH;

  // Weights as A-fragments (same chunked layout/reads as all prior rounds).
  __shared__ __align__(16) short wih0L[2][NG][8];   // K=16: k<10 weights, k=10 bias col, rest 0
  __shared__ __align__(16) short whh0L[4][NG][8];
  __shared__ __align__(16) short wih1L[4][NG][8];
  __shared__ __align__(16) short whh1L[4][NG][8];
  __shared__ __align__(16) short tsg[NW][64][16];   // t (k=0..9), 1.0 at k=10, 0 pad
  __shared__ __align__(16) short tbuf[NW][16][TPS]; // per-wave bf16 h0n regroup buffer

  const int tid = threadIdx.x;
  const int lane = tid & 63;
  const int w = tid >> 6;
  const int col = lane & 15;
  const int g = lane >> 4;

  // ---- bijective XCD-aware swizzle (T1, m204): contiguous chunk per XCD ----
  const int nwg = gridDim.x;
  const int q = nwg >> 3, r8 = nwg & 7;
  const int xcd = blockIdx.x & 7, bidx = blockIdx.x >> 3;
  const int swz = (xcd < r8 ? xcd * (q + 1) : r8 * (q + 1) + (xcd - r8) * q) + bidx;

  const int ebase = swz * (NW * 64) + w * 64;
  const bool active = ebase < BNi;                   // wave-uniform tail guard

  // prefetch state: named scalars only
  float4 Ahv0, Ahv1, Awv0, Awv1;
  float4 Bhv0, Bhv1, Bwv0, Bwv1;
  if (active) LOADH(A, 0);   // in flight across staging + t-MLP + barrier

  for (int idx = tid; idx < NG * HH; idx += BLK) {  // 4096
    int n = idx >> 5, k = idx & 31;
    whh0L[k >> 3][n][k & 7] = f2bf(Whh0[n * HH + k]);
    wih1L[k >> 3][n][k & 7] = f2bf(Wih1[n * HH + k]);
    whh1L[k >> 3][n][k & 7] = f2bf(Whh1[n * HH + k]);
  }
  for (int idx = tid; idx < NG * 16; idx += BLK) {  // 2048
    int n = idx >> 4, k = idx & 15;
    short v;
    if (k < LL)       v = f2bf(Wih0[n * LL + k]);
    else if (k == LL) v = f2bf(bih0[n] + bhh0[n]);  // bias column (t[10]=1)
    else              v = 0;
    wih0L[k >> 3][n][k & 7] = v;
  }

  // layer-1 bias in C-layout: biasv1[nt][r] = b(16nt+4g+r), aligned float4 loads
  f32x4 biasv1[8];
#pragma unroll
  for (int nt = 0; nt < 8; ++nt) {
    float4 a = *reinterpret_cast<const float4*>(bih1 + nt * 16 + 4 * g);
    float4 b = *reinterpret_cast<const float4*>(bhh1 + nt * 16 + 4 * g);
    f32x4 s = {a.x + b.x, a.y + b.y, a.z + b.z, a.w + b.w};
    biasv1[nt] = s;
  }
  float4 wfcA = *reinterpret_cast<const float4*>(Wfc + 4 * g);
  float4 wfcB = *reinterpret_cast<const float4*>(Wfc + 16 + 4 * g);
  const float bfcv = bfc[0];

  if (active) { // ---- t-MLP: one element per lane ----
    float gv = grad[ebase + lane];
    float sg = (gv > 0.f) ? 1.f : ((gv < 0.f) ? -1.f : 0.f);
    float lg = __logf(fabsf(gv) + 1e-14f);
    float u[LL], t[LL];
#pragma unroll
    for (int j = 0; j < LL; ++j)
      u[j] = ftanh(W1[2 * j] * sg + W1[2 * j + 1] * lg + b1[j]);
#pragma unroll
    for (int j = 0; j < LL; ++j) {
      float a = b2[j];
#pragma unroll
      for (int k = 0; k < LL; ++k) a += W2[j * LL + k] * u[k];
      t[j] = a;
    }
    bf16x8 tv0, tv1;
#pragma unroll
    for (int s = 0; s < 8; ++s) tv0[s] = f2bf(t[s]);
    tv1[0] = f2bf(t[8]); tv1[1] = f2bf(t[9]);
    tv1[2] = 0x3F80;                      // bf16 1.0 — bias column multiplier
#pragma unroll
    for (int s = 3; s < 8; ++s) tv1[s] = 0;
    *reinterpret_cast<bf16x8*>(&tsg[w][lane][0]) = tv0;
    *reinterpret_cast<bf16x8*>(&tsg[w][lane][8]) = tv1;
  }
  __syncthreads();

  if (active) {
    LOADH(B, 1);
    COMPUTE(A, 0);
    LOADH(A, 2);
    COMPUTE(B, 1);
    LOADH(B, 3);
    COMPUTE(A, 2);
    COMPUTE(B, 3);
  }
}

extern "C" void kernel_launch(void* const* d_in, const int* in_sizes, int n_in,
                              void* d_out, int out_size, void* d_ws, size_t ws_size,
                              hipStream_t stream) {
  const float* x    = (const float*)d_in[0];
  const float* grad = (const float*)d_in[1];
  const float* h0   = (const float*)d_in[2];
  const float* c0   = (const float*)d_in[3];
  const float* h1   = (const float*)d_in[4];
  const float* c1   = (const float*)d_in[5];
  const float* W1   = (const float*)d_in[6];
  const float* b1   = (const float*)d_in[7];
  const float* W2   = (const float*)d_in[8];
  const float* b2   = (const float*)d_in[9];
  const float* Wih0 = (const float*)d_in[10];
  const float* Whh0 = (const float*)d_in[11];
  const float* bih0 = (const float*)d_in[12];
  const float* bhh0 = (const float*)d_in[13];
  const float* Wih1 = (const float*)d_in[14];
  const float* Whh1 = (const float*)d_in[15];
  const float* bih1 = (const float*)d_in[16];
  const float* bhh1 = (const float*)d_in[17];
  const float* Wfc  = (const float*)d_in[18];
  const float* bfc  = (const float*)d_in[19];
  const int BN = in_sizes[0];            // 800000
  const int nblk = (BN + BLK - 1) / BLK; // 1563 blocks x (8 waves x 64 elems)
  l2o_fused<<<nblk, BLK, 0, stream>>>(x, grad, h0, c0, h1, c1, W1, b1, W2, b2,
                                      Wih0, Whh0, bih0, bhh0, Wih1, Whh1,
                                      bih1, bhh1, Wfc, bfc, (float*)d_out, BN);
}